// Round 12
// baseline (259.721 us; speedup 1.0000x reference)
//
#include <hip/hip_runtime.h>

#define B_TOT 65536
#define T_LEN 34
#define HD 64
#define LOG2E 1.44269504088896340736f

typedef __attribute__((ext_vector_type(8))) short short8b;
typedef __attribute__((ext_vector_type(4))) short short4b;
typedef __attribute__((ext_vector_type(4))) float f32x4;
typedef __attribute__((ext_vector_type(4))) unsigned int u32x4;

__device__ __forceinline__ float frcp(float x){ return __builtin_amdgcn_rcpf(x); }
__device__ __forceinline__ float fexp2(float x){ return __builtin_amdgcn_exp2f(x); }
__device__ __forceinline__ float fsigmoid(float x){ return frcp(1.0f+__expf(-x)); }
__device__ __forceinline__ float felu(float x){ return x>0.0f ? x : (__expf(x)-1.0f); }

__device__ __forceinline__ unsigned short f2bf_rne(float f){
    unsigned int u = __float_as_uint(f);
    u += 0x7FFFu + ((u >> 16) & 1u);
    return (unsigned short)(u >> 16);
}
__device__ __forceinline__ float bf2f(unsigned short h){
    return __uint_as_float(((unsigned int)h) << 16);
}
__device__ __forceinline__ void split8(const float4& a, const float4& b,
                                       short8b& hi, short8b& lo){
    float f[8] = {a.x,a.y,a.z,a.w,b.x,b.y,b.z,b.w};
    #pragma unroll
    for (int i = 0; i < 8; ++i){
        unsigned short h = f2bf_rne(f[i]);
        hi[i] = (short)h;
        lo[i] = (short)f2bf_rne(f[i] - bf2f(h));
    }
}
__device__ __forceinline__ unsigned int cvt_pk_bf16(float lo, float hi){
    unsigned int r;
    asm("v_cvt_pk_bf16_f32 %0, %1, %2" : "=v"(r) : "v"(lo), "v"(hi));
    return r;
}
__device__ __forceinline__ int hswz(int r){ return ((r ^ (r >> 3)) & 7); }

// ---------------- Kernel A: forward-fill + GRU (MFMA) + attention pooling ----------------
// 768 threads, 12 waves, 64 rows/block, 4 row-groups of 16 rows. Each group:
// 2 producer waves (each owns 2 of 4 unit-groups; halved trans chain) + 1 pool
// wave. HL double-buffered; one barrier/t-step. LDS 54 KB -> 2 blocks/CU =
// 24 waves/CU (75% occ). Replicated score tiles; biasN folded in anh C-init.
__global__ __launch_bounds__(768)
void gru_attn_mfma(const float* __restrict__ Xin, const float* __restrict__ FA,
                   const float* __restrict__ Wih, const float* __restrict__ Whh,
                   const float* __restrict__ bih, const float* __restrict__ bhh,
                   const float* __restrict__ swT, const float* __restrict__ swM,
                   float* __restrict__ hT_out, float* __restrict__ hM_out)
{
    __shared__ __align__(16) unsigned short WF[28*512];      // 28 KB: 24 gate + 4 score tiles
    __shared__ __align__(16) unsigned short HL[4][2][1024];  // 16 KB: per-group h, double-buffered
    __shared__ unsigned int XF[T_LEN*64];                    // 8.5 KB: [t][brow] packed (x,fv)
    __shared__ __align__(8)  unsigned short XWc[12][16][4];  // 1.5 KB: compact ext rows k=0..2

    const int tid  = threadIdx.x;
    const int lane = tid & 63;
    const int wv   = tid >> 6;        // 0..11
    const int l16  = lane & 15;
    const int lhi  = lane >> 4;
    const bool isPool = (wv >= 8);
    const int grp  = isPool ? (wv - 8) : (wv >> 1);   // row-group 0..3

    // ---- stage gate + score B-fragments (k-permuted) ----
    for (int f = wv; f < 28; f += 12) {
        unsigned short* dst = &WF[f*512 + lane*8];
        if (f < 24) {
            int ks = f / 12, nt = f % 12;
            int u_out = nt*16 + l16;
            float scale = (nt < 8) ? -LOG2E : 2.0f*LOG2E;
            #pragma unroll
            for (int j = 0; j < 8; ++j) {
                int k = ks*32 + lhi*8 + j;
                int u_in = (k & 3)*16 + (k >> 2);          // k-perm
                dst[j] = f2bf_rne(scale*Whh[u_out*64 + u_in]);
            }
        } else {
            int s = f - 24;                                 // 0,1: swT halves; 2,3: swM
            const float* src = (s >= 2) ? swM : swT;
            int ks = s & 1;
            #pragma unroll
            for (int j = 0; j < 8; ++j) {
                int k = ks*32 + lhi*8 + j;
                int u_in = (k & 3)*16 + (k >> 2);
                dst[j] = f2bf_rne(LOG2E*src[u_in]);         // replicated across all 16 cols
            }
        }
    }
    // ---- compact ext tiles: [nt][u16] -> (s*Wih0, s*Wih1, bias, 0) ----
    if (tid < 192) {
        int nt  = tid >> 4;
        int u16 = tid & 15;
        int u_abs = (nt < 8) ? (nt*16 + u16) : (128 + (nt-8)*16 + u16);
        float s = (nt < 8) ? -LOG2E : 2.0f*LOG2E;
        float bias = (nt < 8) ? -LOG2E*(bih[u_abs] + bhh[u_abs])
                              : 2.0f*LOG2E*bih[u_abs];
        XWc[nt][u16][0] = f2bf_rne(s*Wih[u_abs*2]);
        XWc[nt][u16][1] = f2bf_rne(s*Wih[u_abs*2+1]);
        XWc[nt][u16][2] = f2bf_rne(bias);
        XWc[nt][u16][3] = 0;
    }
    // ---- zero both h buffers ----
    for (int i = tid; i < 4*2*1024; i += 768)
        (&HL[0][0][0])[i] = 0;

    // ---- forward fill (segmented LOCF); lane = time ----
    for (int brow = wv; brow < 64; brow += 12) {
        int row = blockIdx.x*64 + brow;
        float X = 0.0f, fa = 0.0f; int idx = -1;
        if (lane < T_LEN) {
            X  = Xin[row*T_LEN + lane];
            fa = FA [row*T_LEN + lane];
            if (X != 0.0f) idx = lane;
        }
        #pragma unroll
        for (int off = 1; off < 64; off <<= 1) {
            int v = __shfl_up(idx, off);
            if (lane >= off && v > idx) idx = v;
        }
        int gsrc = idx < 0 ? 0 : idx;
        float Xg = __shfl(X,  gsrc);
        float fg = __shfl(fa, gsrc);
        if (idx < 0) { Xg = 0.0f; fg = 0.0f; }
        if (lane < T_LEN)
            XF[lane*64 + brow] =
                (unsigned int)f2bf_rne(Xg) | ((unsigned int)f2bf_rne(fg) << 16);
    }

    __syncthreads();

    // common per-lane addresses
    const int sA    = hswz(l16) << 3;                       // in shorts
    const int aoff0 = l16*64 + (( lhi   *8) ^ sA);
    const int aoff1 = l16*64 + (((4+lhi)*8) ^ sA);
    const f32x4 zero4 = (f32x4){0.f, 0.f, 0.f, 0.f};
    const unsigned short* WFl = &WF[lane*8];

    if (!isPool) {
        // ================= GRU producer (half: unit-groups g0, g0+1) =================
        __builtin_amdgcn_s_setprio(1);
        const int g0 = (wv & 1)*2;
        const unsigned int extk2 = (lhi == 0) ? 0x00003f80u : 0u;  // bf16(1.0) in k=2
        const bool ext0 = (lhi == 0);
        const uint2* XWp = reinterpret_cast<const uint2*>(&XWc[0][0][0]);
        f32x4 biasN4[2];
        #pragma unroll
        for (int gg = 0; gg < 2; ++gg) {
            float b = 2.0f*LOG2E*bhh[128 + (g0+gg)*16 + l16];
            biasN4[gg] = (f32x4){b, b, b, b};
        }

        float2 hreg2[4];   // per q: (h[g0*16+l16], h[(g0+1)*16+l16])
        #pragma unroll
        for (int q = 0; q < 4; ++q) hreg2[q] = make_float2(0.f, 0.f);

        for (int t = 0; t < T_LEN; ++t) {
            __syncthreads();
            const unsigned short* pb = &HL[grp][(t+1)&1][0];
            unsigned short*       cb = &HL[grp][ t   &1][0];
            short8b a0 = *reinterpret_cast<const short8b*>(&pb[aoff0]);
            short8b a1 = *reinterpret_cast<const short8b*>(&pb[aoff1]);
            unsigned int xw = XF[t*64 + grp*16 + l16];
            u32x4 aeu = { ext0 ? xw : 0u, extk2, 0u, 0u };
            short8b aext = __builtin_bit_cast(short8b, aeu);

            #pragma unroll
            for (int gg = 0; gg < 2; ++gg) {
                const int g = g0 + gg;
                uint2 er = XWp[(g   )*16 + l16];
                uint2 ez = XWp[(4+g )*16 + l16];
                uint2 en = XWp[(8+g )*16 + l16];
                u32x4 bru = { ext0 ? er.x : 0u, ext0 ? er.y : 0u, 0u, 0u };
                u32x4 bzu = { ext0 ? ez.x : 0u, ext0 ? ez.y : 0u, 0u, 0u };
                u32x4 bnu = { ext0 ? en.x : 0u, ext0 ? en.y : 0u, 0u, 0u };

                f32x4 ar = __builtin_amdgcn_mfma_f32_16x16x32_bf16(
                    aext, __builtin_bit_cast(short8b, bru), zero4, 0,0,0);
                ar = __builtin_amdgcn_mfma_f32_16x16x32_bf16(
                    a0, *reinterpret_cast<const short8b*>(WFl + (g   )*512), ar, 0,0,0);
                ar = __builtin_amdgcn_mfma_f32_16x16x32_bf16(
                    a1, *reinterpret_cast<const short8b*>(WFl + (12+g)*512), ar, 0,0,0);
                f32x4 az = __builtin_amdgcn_mfma_f32_16x16x32_bf16(
                    aext, __builtin_bit_cast(short8b, bzu), zero4, 0,0,0);
                az = __builtin_amdgcn_mfma_f32_16x16x32_bf16(
                    a0, *reinterpret_cast<const short8b*>(WFl + (4+g )*512), az, 0,0,0);
                az = __builtin_amdgcn_mfma_f32_16x16x32_bf16(
                    a1, *reinterpret_cast<const short8b*>(WFl + (16+g)*512), az, 0,0,0);
                f32x4 anx = __builtin_amdgcn_mfma_f32_16x16x32_bf16(
                    aext, __builtin_bit_cast(short8b, bnu), zero4, 0,0,0);
                f32x4 anh = __builtin_amdgcn_mfma_f32_16x16x32_bf16(
                    a0, *reinterpret_cast<const short8b*>(WFl + (8+g )*512), biasN4[gg], 0,0,0);
                anh = __builtin_amdgcn_mfma_f32_16x16x32_bf16(
                    a1, *reinterpret_cast<const short8b*>(WFl + (20+g)*512), anh, 0,0,0);
                #pragma unroll
                for (int q = 0; q < 4; ++q) {
                    float r  = frcp(1.0f + fexp2(ar[q]));
                    float z  = frcp(1.0f + fexp2(az[q]));
                    float v  = fmaf(r, anh[q], anx[q]);
                    float n  = fmaf(-2.0f, frcp(1.0f + fexp2(v)), 1.0f);
                    float h  = gg ? hreg2[q].y : hreg2[q].x;
                    float hn = fmaf(z, h - n, n);
                    if (gg) hreg2[q].y = hn; else hreg2[q].x = hn;
                }
            }
            // packed h writeback: one b32 per q (units g0,g0+1 are adjacent k-perm slots)
            #pragma unroll
            for (int q = 0; q < 4; ++q) {
                int rloc = lhi*4 + q;
                int so = rloc*64 + ((l16*4 + g0) ^ (hswz(rloc) << 3));
                *reinterpret_cast<unsigned int*>(&cb[so]) =
                    cvt_pk_bf16(hreg2[q].x, hreg2[q].y);
            }
        }
        __syncthreads();   // match pool branch's final barrier
    } else {
        // ================= pooling consumer =================
        float2 numT2[4][2], numM2[4][2];
        float  denT[4] = {}, denM[4] = {};
        #pragma unroll
        for (int q = 0; q < 4; ++q)
            #pragma unroll
            for (int j = 0; j < 2; ++j) {
                numT2[q][j] = make_float2(0.f, 0.f);
                numM2[q][j] = make_float2(0.f, 0.f);
            }

        for (int t = 0; t < T_LEN; ++t) {
            __syncthreads();
            if (t == 0) continue;     // h_{-1} not pooled
            const unsigned short* pb = &HL[grp][(t+1)&1][0];   // h_{t-1}
            short8b a0 = *reinterpret_cast<const short8b*>(&pb[aoff0]);
            short8b a1 = *reinterpret_cast<const short8b*>(&pb[aoff1]);
            f32x4 accT = __builtin_amdgcn_mfma_f32_16x16x32_bf16(
                a0, *reinterpret_cast<const short8b*>(WFl + 24*512), zero4, 0,0,0);
            accT = __builtin_amdgcn_mfma_f32_16x16x32_bf16(
                a1, *reinterpret_cast<const short8b*>(WFl + 25*512), accT, 0,0,0);
            f32x4 accM = __builtin_amdgcn_mfma_f32_16x16x32_bf16(
                a0, *reinterpret_cast<const short8b*>(WFl + 26*512), zero4, 0,0,0);
            accM = __builtin_amdgcn_mfma_f32_16x16x32_bf16(
                a1, *reinterpret_cast<const short8b*>(WFl + 27*512), accM, 0,0,0);
            #pragma unroll
            for (int q = 0; q < 4; ++q) {
                int rloc = lhi*4 + q;
                uint2 hq = *reinterpret_cast<const uint2*>(
                    &pb[rloc*64 + ((l16*4) ^ (hswz(rloc) << 3))]);
                float g0v = __uint_as_float(hq.x << 16);
                float g1v = __uint_as_float(hq.x & 0xFFFF0000u);
                float g2v = __uint_as_float(hq.y << 16);
                float g3v = __uint_as_float(hq.y & 0xFFFF0000u);
                float eT = fexp2(accT[q]);
                float eM = fexp2(accM[q]);
                denT[q] += eT; denM[q] += eM;
                numT2[q][0].x = fmaf(eT, g0v, numT2[q][0].x);
                numT2[q][0].y = fmaf(eT, g1v, numT2[q][0].y);
                numT2[q][1].x = fmaf(eT, g2v, numT2[q][1].x);
                numT2[q][1].y = fmaf(eT, g3v, numT2[q][1].y);
                numM2[q][0].x = fmaf(eM, g0v, numM2[q][0].x);
                numM2[q][0].y = fmaf(eM, g1v, numM2[q][0].y);
                numM2[q][1].x = fmaf(eM, g2v, numM2[q][1].x);
                numM2[q][1].y = fmaf(eM, g3v, numM2[q][1].y);
            }
        }
        __syncthreads();   // h_33 (buf[1]) complete
        {
            const unsigned short* pb = &HL[grp][1][0];          // h_33 (33&1 = 1)
            short8b a0 = *reinterpret_cast<const short8b*>(&pb[aoff0]);
            short8b a1 = *reinterpret_cast<const short8b*>(&pb[aoff1]);
            f32x4 accT = __builtin_amdgcn_mfma_f32_16x16x32_bf16(
                a0, *reinterpret_cast<const short8b*>(WFl + 24*512), zero4, 0,0,0);
            accT = __builtin_amdgcn_mfma_f32_16x16x32_bf16(
                a1, *reinterpret_cast<const short8b*>(WFl + 25*512), accT, 0,0,0);
            f32x4 accM = __builtin_amdgcn_mfma_f32_16x16x32_bf16(
                a0, *reinterpret_cast<const short8b*>(WFl + 26*512), zero4, 0,0,0);
            accM = __builtin_amdgcn_mfma_f32_16x16x32_bf16(
                a1, *reinterpret_cast<const short8b*>(WFl + 27*512), accM, 0,0,0);
            #pragma unroll
            for (int q = 0; q < 4; ++q) {
                int rloc = lhi*4 + q;
                uint2 hq = *reinterpret_cast<const uint2*>(
                    &pb[rloc*64 + ((l16*4) ^ (hswz(rloc) << 3))]);
                float g0v = __uint_as_float(hq.x << 16);
                float g1v = __uint_as_float(hq.x & 0xFFFF0000u);
                float g2v = __uint_as_float(hq.y << 16);
                float g3v = __uint_as_float(hq.y & 0xFFFF0000u);
                float eT = fexp2(accT[q]);
                float eM = fexp2(accM[q]);
                denT[q] += eT; denM[q] += eM;
                numT2[q][0].x = fmaf(eT, g0v, numT2[q][0].x);
                numT2[q][0].y = fmaf(eT, g1v, numT2[q][0].y);
                numT2[q][1].x = fmaf(eT, g2v, numT2[q][1].x);
                numT2[q][1].y = fmaf(eT, g3v, numT2[q][1].y);
                numM2[q][0].x = fmaf(eM, g0v, numM2[q][0].x);
                numM2[q][0].y = fmaf(eM, g1v, numM2[q][0].y);
                numM2[q][1].x = fmaf(eM, g2v, numM2[q][1].x);
                numM2[q][1].y = fmaf(eM, g3v, numM2[q][1].y);
            }
        }
        const int rowbase = blockIdx.x*64 + grp*16;
        #pragma unroll
        for (int q = 0; q < 4; ++q) {
            int row = rowbase + lhi*4 + q;
            float rT = frcp(denT[q]), rM = frcp(denM[q]);
            #pragma unroll
            for (int j = 0; j < 2; ++j) {
                hT_out[row*HD + (2*j  )*16 + l16] = numT2[q][j].x*rT;
                hT_out[row*HD + (2*j+1)*16 + l16] = numT2[q][j].y*rT;
                hM_out[row*HD + (2*j  )*16 + l16] = numM2[q][j].x*rM;
                hM_out[row*HD + (2*j+1)*16 + l16] = numM2[q][j].y*rM;
            }
        }
    }
}

// ---------------- Kernel B: MFMA MLP heads + T10/M0 + X_out (unchanged) ----------------
__global__ __launch_bounds__(256)
void mlp_mfma(const float* __restrict__ hT, const float* __restrict__ hM,
    const float* __restrict__ TW1, const float* __restrict__ Tb1,
    const float* __restrict__ TW2, const float* __restrict__ Tb2,
    const float* __restrict__ TW3, const float* __restrict__ Tb3,
    const float* __restrict__ MW1, const float* __restrict__ Mb1,
    const float* __restrict__ MW2, const float* __restrict__ Mb2,
    const float* __restrict__ MW3, const float* __restrict__ Mb3,
    const float* __restrict__ FA, const float* __restrict__ TR,
    float* __restrict__ out)
{
    __shared__ __align__(16) unsigned short xh[2*64*64];
    __shared__ __align__(16) unsigned short h1s[64*256];
    __shared__ float praw[4][64];
    __shared__ float rawv[2][64];
    __shared__ float Es[64], M0s[64];

    const int tid  = threadIdx.x;
    const int lane = tid & 63;
    const int wv   = tid >> 6;
    const int l16  = lane & 15;
    const int lhi  = lane >> 4;
    const int row0 = blockIdx.x*64;

    {
        int r  = tid >> 2;
        int k0 = (tid & 3) * 16;
        int rx = r & 7;
        const float* pT = &hT[(row0+r)*64 + k0];
        const float* pM = &hM[(row0+r)*64 + k0];
        #pragma unroll
        for (int j = 0; j < 4; ++j) {
            float4 vT = *reinterpret_cast<const float4*>(pT + 4*j);
            float4 vM = *reinterpret_cast<const float4*>(pM + 4*j);
            int kk = k0 + 4*j;
            int ad = r*64 + ((((kk>>3) ^ rx))<<3) + (kk&7);
            short4b sT = { (short)f2bf_rne(vT.x), (short)f2bf_rne(vT.y),
                           (short)f2bf_rne(vT.z), (short)f2bf_rne(vT.w) };
            short4b sM = { (short)f2bf_rne(vM.x), (short)f2bf_rne(vM.y),
                           (short)f2bf_rne(vM.z), (short)f2bf_rne(vM.w) };
            *reinterpret_cast<short4b*>(&xh[ad])        = sT;
            *reinterpret_cast<short4b*>(&xh[4096 + ad]) = sM;
        }
        for (int i = tid; i < 64*24; i += 256) {
            int rr = i / 24, kk = 200 + i % 24;
            h1s[rr*256 + ((((kk>>3) ^ (rr&7)))<<3) + (kk&7)] = 0;
        }
    }
    __syncthreads();

    for (int brn = 0; brn < 2; ++brn) {
        const float* W1 = brn ? MW1 : TW1; const float* b1 = brn ? Mb1 : Tb1;
        const float* W2 = brn ? MW2 : TW2; const float* b2 = brn ? Mb2 : Tb2;
        const float* W3 = brn ? MW3 : TW3; const float* b3 = brn ? Mb3 : Tb3;

        for (int s = 0; s < 4; ++s) {
            int nt = wv + 4*s;
            if (nt > 12) break;
            int n  = nt*16 + l16;
            int nc = n < 200 ? n : 199;
            float bv = b1[nc];
            f32x4 acc[4];
            #pragma unroll
            for (int mt = 0; mt < 4; ++mt) acc[mt] = (f32x4){bv,bv,bv,bv};
            #pragma unroll
            for (int ks = 0; ks < 2; ++ks) {
                int k0 = ks*32 + lhi*8;
                const float* wp = &W1[nc*64 + k0];
                float4 w0 = *reinterpret_cast<const float4*>(wp);
                float4 w1 = *reinterpret_cast<const float4*>(wp + 4);
                short8b bh, bl;
                split8(w0, w1, bh, bl);
                #pragma unroll
                for (int mt = 0; mt < 4; ++mt) {
                    int rr = mt*16 + l16;
                    short8b a = *reinterpret_cast<const short8b*>(
                        &xh[brn*4096 + rr*64 + ((((k0>>3) ^ (rr&7)))<<3)]);
                    acc[mt] = __builtin_amdgcn_mfma_f32_16x16x32_bf16(a, bh, acc[mt], 0,0,0);
                    acc[mt] = __builtin_amdgcn_mfma_f32_16x16x32_bf16(a, bl, acc[mt], 0,0,0);
                }
            }
            if (n < 200) {
                #pragma unroll
                for (int mt = 0; mt < 4; ++mt) {
                    #pragma unroll
                    for (int q = 0; q < 4; ++q) {
                        int rr = mt*16 + lhi*4 + q;
                        h1s[rr*256 + ((((n>>3) ^ (rr&7)))<<3) + (n&7)] =
                            f2bf_rne(felu(acc[mt][q]));
                    }
                }
            }
        }
        __syncthreads();

        float p[4][4] = {};
        for (int s = 0; s < 4; ++s) {
            int nt = wv + 4*s;
            if (nt > 12) break;
            int n  = nt*16 + l16;
            int nc = n < 200 ? n : 199;
            float w3v = (n < 200) ? W3[nc] : 0.0f;
            float bv = b2[nc];
            f32x4 acc[4];
            #pragma unroll
            for (int mt = 0; mt < 4; ++mt) acc[mt] = (f32x4){bv,bv,bv,bv};
            for (int ks = 0; ks < 7; ++ks) {
                int k0 = ks*32 + lhi*8;
                short8b bh, bl;
                if (k0 + 8 <= 200) {
                    const float* wp = &W2[nc*200 + k0];
                    float4 w0 = *reinterpret_cast<const float4*>(wp);
                    float4 w1 = *reinterpret_cast<const float4*>(wp + 4);
                    split8(w0, w1, bh, bl);
                } else {
                    #pragma unroll
                    for (int i = 0; i < 8; ++i) { bh[i] = 0; bl[i] = 0; }
                }
                #pragma unroll
                for (int mt = 0; mt < 4; ++mt) {
                    int rr = mt*16 + l16;
                    short8b a = *reinterpret_cast<const short8b*>(
                        &h1s[rr*256 + ((((k0>>3) ^ (rr&7)))<<3)]);
                    acc[mt] = __builtin_amdgcn_mfma_f32_16x16x32_bf16(a, bh, acc[mt], 0,0,0);
                    acc[mt] = __builtin_amdgcn_mfma_f32_16x16x32_bf16(a, bl, acc[mt], 0,0,0);
                }
            }
            #pragma unroll
            for (int mt = 0; mt < 4; ++mt)
                #pragma unroll
                for (int q = 0; q < 4; ++q)
                    p[mt][q] = fmaf(w3v, felu(acc[mt][q]), p[mt][q]);
        }
        #pragma unroll
        for (int off = 1; off < 16; off <<= 1) {
            #pragma unroll
            for (int mt = 0; mt < 4; ++mt)
                #pragma unroll
                for (int q = 0; q < 4; ++q)
                    p[mt][q] += __shfl_xor(p[mt][q], off);
        }
        if (l16 == 0) {
            #pragma unroll
            for (int mt = 0; mt < 4; ++mt)
                #pragma unroll
                for (int q = 0; q < 4; ++q)
                    praw[wv][mt*16 + lhi*4 + q] = p[mt][q];
        }
        __syncthreads();
        if (tid < 64)
            rawv[brn][tid] = b3[0] + praw[0][tid] + praw[1][tid] + praw[2][tid] + praw[3][tid];
        __syncthreads();
    }

    if (tid < 64) {
        int row = row0 + tid;
        float T10 = 0.1f + 4.9f*fsigmoid(rawv[0][tid]);
        float M0  = 10000.0f*fsigmoid(rawv[1][tid]);
        Es[tid]  = __expf(-TR[row]/T10);
        M0s[tid] = M0;
        out[(size_t)B_TOT*T_LEN + row]         = T10;
        out[(size_t)B_TOT*T_LEN + B_TOT + row] = M0;
    }
    __syncthreads();
    for (int i = tid; i < 64*T_LEN; i += 256) {
        int rr = i / T_LEN, t = i - rr*T_LEN;
        int row = row0 + rr;
        float fa = FA[row*T_LEN + t];
        float s = __sinf(fa), c = __cosf(fa);
        float Ev = Es[rr];
        out[row*T_LEN + t] = (1.0f - Ev)*s*frcp(1.0f - c*Ev)*M0s[rr];
    }
}

extern "C" void kernel_launch(void* const* d_in, const int* in_sizes, int n_in,
                              void* d_out, int out_size, void* d_ws, size_t ws_size,
                              hipStream_t stream) {
    const float* Xin = (const float*)d_in[0];
    const float* FA  = (const float*)d_in[1];
    const float* TR  = (const float*)d_in[4];
    const float* Wih = (const float*)d_in[5];
    const float* Whh = (const float*)d_in[6];
    const float* bih = (const float*)d_in[7];
    const float* bhh = (const float*)d_in[8];
    const float* swT = (const float*)d_in[9];
    const float* swM = (const float*)d_in[10];
    const float* TW1 = (const float*)d_in[11]; const float* Tb1 = (const float*)d_in[12];
    const float* TW2 = (const float*)d_in[13]; const float* Tb2 = (const float*)d_in[14];
    const float* TW3 = (const float*)d_in[15]; const float* Tb3 = (const float*)d_in[16];
    const float* MW1 = (const float*)d_in[17]; const float* Mb1 = (const float*)d_in[18];
    const float* MW2 = (const float*)d_in[19]; const float* Mb2 = (const float*)d_in[20];
    const float* MW3 = (const float*)d_in[21]; const float* Mb3 = (const float*)d_in[22];
    float* out = (float*)d_out;

    float* hT = (float*)d_ws;
    float* hM = hT + (size_t)B_TOT*HD;

    gru_attn_mfma<<<B_TOT/64, 768, 0, stream>>>(Xin, FA, Wih, Whh, bih, bhh,
                                                swT, swM, hT, hM);
    mlp_mfma<<<B_TOT/64, 256, 0, stream>>>(hT, hM,
                                           TW1, Tb1, TW2, Tb2, TW3, Tb3,
                                           MW1, Mb1, MW2, Mb2, MW3, Mb3,
                                           FA, TR, out);
}

// Round 13
// 241.043 us; speedup vs baseline: 1.0775x; 1.0775x over previous
//
#include <hip/hip_runtime.h>

#define B_TOT 65536
#define T_LEN 34
#define HD 64
#define LOG2E 1.44269504088896340736f

typedef __attribute__((ext_vector_type(8))) short short8b;
typedef __attribute__((ext_vector_type(4))) short short4b;
typedef __attribute__((ext_vector_type(4))) float f32x4;
typedef __attribute__((ext_vector_type(4))) unsigned int u32x4;

__device__ __forceinline__ float frcp(float x){ return __builtin_amdgcn_rcpf(x); }
__device__ __forceinline__ float fexp2(float x){ return __builtin_amdgcn_exp2f(x); }
__device__ __forceinline__ float fsigmoid(float x){ return frcp(1.0f+__expf(-x)); }
__device__ __forceinline__ float felu(float x){ return x>0.0f ? x : (__expf(x)-1.0f); }

__device__ __forceinline__ unsigned short f2bf_rne(float f){
    unsigned int u = __float_as_uint(f);
    u += 0x7FFFu + ((u >> 16) & 1u);
    return (unsigned short)(u >> 16);
}
__device__ __forceinline__ float bf2f(unsigned short h){
    return __uint_as_float(((unsigned int)h) << 16);
}
__device__ __forceinline__ void split8(const float4& a, const float4& b,
                                       short8b& hi, short8b& lo){
    float f[8] = {a.x,a.y,a.z,a.w,b.x,b.y,b.z,b.w};
    #pragma unroll
    for (int i = 0; i < 8; ++i){
        unsigned short h = f2bf_rne(f[i]);
        hi[i] = (short)h;
        lo[i] = (short)f2bf_rne(f[i] - bf2f(h));
    }
}
__device__ __forceinline__ unsigned int cvt_pk_bf16(float lo, float hi){
    unsigned int r;
    asm("v_cvt_pk_bf16_f32 %0, %1, %2" : "=v"(r) : "v"(lo), "v"(hi));
    return r;
}
__device__ __forceinline__ int hswz(int r){ return ((r ^ (r >> 3)) & 7); }

// ---------------- Kernel A: forward-fill + GRU (MFMA) + attention pooling ----------------
// Round-9 structure (empirical optimum of rounds 9-12): 512 threads, waves 0-3
// GRU producers (16 rows each), waves 4-7 pooling consumers. HL double-buffered;
// one barrier per t-step. Role split keeps hreg (GRU) and num/den (pool) in
// separate register allocations (VGPR ~64 -> 43% occupancy). biasN folded into
// the anh MFMA C-init (r11-verified, -16 fma/lane/step).
__global__ __launch_bounds__(512)
void gru_attn_mfma(const float* __restrict__ Xin, const float* __restrict__ FA,
                   const float* __restrict__ Wih, const float* __restrict__ Whh,
                   const float* __restrict__ bih, const float* __restrict__ bhh,
                   const float* __restrict__ swT, const float* __restrict__ swM,
                   float* __restrict__ hT_out, float* __restrict__ hM_out)
{
    __shared__ __align__(16) unsigned short WF[28*512];      // 28 KB: 24 gate + 4 score tiles
    __shared__ __align__(16) unsigned short HL[4][2][1024];  // 16 KB: per-pair h, double-buffered
    __shared__ unsigned int XF[T_LEN*64];                    // 8.5 KB: [t][brow] packed (x,fv)
    __shared__ __align__(8)  unsigned short XWc[12][16][4];  // 1.5 KB: compact ext rows k=0..2

    const int tid  = threadIdx.x;
    const int lane = tid & 63;
    const int wv   = tid >> 6;        // 0..7
    const int l16  = lane & 15;
    const int lhi  = lane >> 4;
    const int wgru = wv & 3;          // row-group owner (shared by producer+consumer)
    const bool isPool = (wv >= 4);

    // ---- stage gate + score B-fragments (k-permuted) ----
    for (int f = wv; f < 28; f += 8) {
        unsigned short* dst = &WF[f*512 + lane*8];
        if (f < 24) {
            int ks = f / 12, nt = f % 12;
            int u_out = nt*16 + l16;
            float scale = (nt < 8) ? -LOG2E : 2.0f*LOG2E;
            #pragma unroll
            for (int j = 0; j < 8; ++j) {
                int k = ks*32 + lhi*8 + j;
                int u_in = (k & 3)*16 + (k >> 2);          // k-perm
                dst[j] = f2bf_rne(scale*Whh[u_out*64 + u_in]);
            }
        } else {
            int s = f - 24;                                 // 0,1: swT halves; 2,3: swM
            const float* src = (s >= 2) ? swM : swT;
            int ks = s & 1;
            #pragma unroll
            for (int j = 0; j < 8; ++j) {
                int k = ks*32 + lhi*8 + j;
                int u_in = (k & 3)*16 + (k >> 2);
                dst[j] = f2bf_rne(LOG2E*src[u_in]);         // replicated across all 16 cols
            }
        }
    }
    // ---- compact ext tiles: [nt][u16] -> (s*Wih0, s*Wih1, bias, 0) ----
    if (tid < 192) {
        int nt  = tid >> 4;
        int u16 = tid & 15;
        int u_abs = (nt < 8) ? (nt*16 + u16) : (128 + (nt-8)*16 + u16);
        float s = (nt < 8) ? -LOG2E : 2.0f*LOG2E;
        float bias = (nt < 8) ? -LOG2E*(bih[u_abs] + bhh[u_abs])
                              : 2.0f*LOG2E*bih[u_abs];
        XWc[nt][u16][0] = f2bf_rne(s*Wih[u_abs*2]);
        XWc[nt][u16][1] = f2bf_rne(s*Wih[u_abs*2+1]);
        XWc[nt][u16][2] = f2bf_rne(bias);
        XWc[nt][u16][3] = 0;
    }
    // ---- zero both h buffers ----
    for (int i = tid; i < 4*2*1024; i += 512)
        (&HL[0][0][0])[i] = 0;

    // ---- forward fill (segmented LOCF); lane = time; 8 rows per wave ----
    for (int i = 0; i < 8; ++i) {
        int brow = wv*8 + i;
        int row  = blockIdx.x*64 + brow;
        float X = 0.0f, fa = 0.0f; int idx = -1;
        if (lane < T_LEN) {
            X  = Xin[row*T_LEN + lane];
            fa = FA [row*T_LEN + lane];
            if (X != 0.0f) idx = lane;
        }
        #pragma unroll
        for (int off = 1; off < 64; off <<= 1) {
            int v = __shfl_up(idx, off);
            if (lane >= off && v > idx) idx = v;
        }
        int gsrc = idx < 0 ? 0 : idx;
        float Xg = __shfl(X,  gsrc);
        float fg = __shfl(fa, gsrc);
        if (idx < 0) { Xg = 0.0f; fg = 0.0f; }
        if (lane < T_LEN)
            XF[lane*64 + brow] =
                (unsigned int)f2bf_rne(Xg) | ((unsigned int)f2bf_rne(fg) << 16);
    }

    __syncthreads();

    // common per-lane addresses
    const int sA    = hswz(l16) << 3;                       // in shorts
    const int aoff0 = l16*64 + (( lhi   *8) ^ sA);
    const int aoff1 = l16*64 + (((4+lhi)*8) ^ sA);
    const f32x4 zero4 = (f32x4){0.f, 0.f, 0.f, 0.f};
    const unsigned short* WFl = &WF[lane*8];

    if (!isPool) {
        // ================= GRU producer =================
        __builtin_amdgcn_s_setprio(1);
        const unsigned int extk2 = (lhi == 0) ? 0x00003f80u : 0u;  // bf16(1.0) in k=2
        const bool ext0 = (lhi == 0);
        const uint2* XWp = reinterpret_cast<const uint2*>(&XWc[0][0][0]);
        f32x4 biasN4[4];
        #pragma unroll
        for (int g = 0; g < 4; ++g) {
            float b = 2.0f*LOG2E*bhh[128 + g*16 + l16];
            biasN4[g] = (f32x4){b, b, b, b};
        }

        float2 hreg2[4][2];
        #pragma unroll
        for (int q = 0; q < 4; ++q) { hreg2[q][0] = make_float2(0.f,0.f);
                                      hreg2[q][1] = make_float2(0.f,0.f); }

        for (int t = 0; t < T_LEN; ++t) {
            __syncthreads();
            const unsigned short* pb = &HL[wgru][(t+1)&1][0];
            unsigned short*       cb = &HL[wgru][ t   &1][0];
            short8b a0 = *reinterpret_cast<const short8b*>(&pb[aoff0]);
            short8b a1 = *reinterpret_cast<const short8b*>(&pb[aoff1]);
            unsigned int xw = XF[t*64 + wgru*16 + l16];
            u32x4 aeu = { ext0 ? xw : 0u, extk2, 0u, 0u };
            short8b aext = __builtin_bit_cast(short8b, aeu);

            #pragma unroll
            for (int g = 0; g < 4; ++g) {
                uint2 er = XWp[(g   )*16 + l16];
                uint2 ez = XWp[(4+g )*16 + l16];
                uint2 en = XWp[(8+g )*16 + l16];
                u32x4 bru = { ext0 ? er.x : 0u, ext0 ? er.y : 0u, 0u, 0u };
                u32x4 bzu = { ext0 ? ez.x : 0u, ext0 ? ez.y : 0u, 0u, 0u };
                u32x4 bnu = { ext0 ? en.x : 0u, ext0 ? en.y : 0u, 0u, 0u };

                f32x4 ar = __builtin_amdgcn_mfma_f32_16x16x32_bf16(
                    aext, __builtin_bit_cast(short8b, bru), zero4, 0,0,0);
                ar = __builtin_amdgcn_mfma_f32_16x16x32_bf16(
                    a0, *reinterpret_cast<const short8b*>(WFl + (g   )*512), ar, 0,0,0);
                ar = __builtin_amdgcn_mfma_f32_16x16x32_bf16(
                    a1, *reinterpret_cast<const short8b*>(WFl + (12+g)*512), ar, 0,0,0);
                f32x4 az = __builtin_amdgcn_mfma_f32_16x16x32_bf16(
                    aext, __builtin_bit_cast(short8b, bzu), zero4, 0,0,0);
                az = __builtin_amdgcn_mfma_f32_16x16x32_bf16(
                    a0, *reinterpret_cast<const short8b*>(WFl + (4+g )*512), az, 0,0,0);
                az = __builtin_amdgcn_mfma_f32_16x16x32_bf16(
                    a1, *reinterpret_cast<const short8b*>(WFl + (16+g)*512), az, 0,0,0);
                f32x4 anx = __builtin_amdgcn_mfma_f32_16x16x32_bf16(
                    aext, __builtin_bit_cast(short8b, bnu), zero4, 0,0,0);
                f32x4 anh = __builtin_amdgcn_mfma_f32_16x16x32_bf16(
                    a0, *reinterpret_cast<const short8b*>(WFl + (8+g )*512), biasN4[g], 0,0,0);
                anh = __builtin_amdgcn_mfma_f32_16x16x32_bf16(
                    a1, *reinterpret_cast<const short8b*>(WFl + (20+g)*512), anh, 0,0,0);
                #pragma unroll
                for (int q = 0; q < 4; ++q) {
                    float r  = frcp(1.0f + fexp2(ar[q]));
                    float z  = frcp(1.0f + fexp2(az[q]));
                    float v  = fmaf(r, anh[q], anx[q]);
                    float n  = fmaf(-2.0f, frcp(1.0f + fexp2(v)), 1.0f);
                    float h  = (g & 1) ? hreg2[q][g>>1].y : hreg2[q][g>>1].x;
                    float hn = fmaf(z, h - n, n);
                    if (g & 1) hreg2[q][g>>1].y = hn; else hreg2[q][g>>1].x = hn;
                }
            }
            // packed h writeback: one b64 per q (k-permuted layout)
            #pragma unroll
            for (int q = 0; q < 4; ++q) {
                int rloc = lhi*4 + q;
                unsigned int d0 = cvt_pk_bf16(hreg2[q][0].x, hreg2[q][0].y);
                unsigned int d1 = cvt_pk_bf16(hreg2[q][1].x, hreg2[q][1].y);
                int so = rloc*64 + ((l16*4) ^ (hswz(rloc) << 3));
                *reinterpret_cast<uint2*>(&cb[so]) = make_uint2(d0, d1);
            }
        }
        __syncthreads();   // match pool branch's final barrier
    } else {
        // ================= pooling consumer =================
        float2 numT2[4][2], numM2[4][2];
        float  denT[4] = {}, denM[4] = {};
        #pragma unroll
        for (int q = 0; q < 4; ++q)
            #pragma unroll
            for (int j = 0; j < 2; ++j) {
                numT2[q][j] = make_float2(0.f, 0.f);
                numM2[q][j] = make_float2(0.f, 0.f);
            }

        for (int t = 0; t < T_LEN; ++t) {
            __syncthreads();
            if (t == 0) continue;     // h_{-1} not pooled
            const unsigned short* pb = &HL[wgru][(t+1)&1][0];   // h_{t-1}
            short8b a0 = *reinterpret_cast<const short8b*>(&pb[aoff0]);
            short8b a1 = *reinterpret_cast<const short8b*>(&pb[aoff1]);
            f32x4 accT = __builtin_amdgcn_mfma_f32_16x16x32_bf16(
                a0, *reinterpret_cast<const short8b*>(WFl + 24*512), zero4, 0,0,0);
            accT = __builtin_amdgcn_mfma_f32_16x16x32_bf16(
                a1, *reinterpret_cast<const short8b*>(WFl + 25*512), accT, 0,0,0);
            f32x4 accM = __builtin_amdgcn_mfma_f32_16x16x32_bf16(
                a0, *reinterpret_cast<const short8b*>(WFl + 26*512), zero4, 0,0,0);
            accM = __builtin_amdgcn_mfma_f32_16x16x32_bf16(
                a1, *reinterpret_cast<const short8b*>(WFl + 27*512), accM, 0,0,0);
            #pragma unroll
            for (int q = 0; q < 4; ++q) {
                int rloc = lhi*4 + q;
                uint2 hq = *reinterpret_cast<const uint2*>(
                    &pb[rloc*64 + ((l16*4) ^ (hswz(rloc) << 3))]);
                float g0 = __uint_as_float(hq.x << 16);
                float g1 = __uint_as_float(hq.x & 0xFFFF0000u);
                float g2 = __uint_as_float(hq.y << 16);
                float g3 = __uint_as_float(hq.y & 0xFFFF0000u);
                float eT = fexp2(accT[q]);
                float eM = fexp2(accM[q]);
                denT[q] += eT; denM[q] += eM;
                numT2[q][0].x = fmaf(eT, g0, numT2[q][0].x);
                numT2[q][0].y = fmaf(eT, g1, numT2[q][0].y);
                numT2[q][1].x = fmaf(eT, g2, numT2[q][1].x);
                numT2[q][1].y = fmaf(eT, g3, numT2[q][1].y);
                numM2[q][0].x = fmaf(eM, g0, numM2[q][0].x);
                numM2[q][0].y = fmaf(eM, g1, numM2[q][0].y);
                numM2[q][1].x = fmaf(eM, g2, numM2[q][1].x);
                numM2[q][1].y = fmaf(eM, g3, numM2[q][1].y);
            }
        }
        __syncthreads();   // h_33 (buf[1]) complete
        {
            const unsigned short* pb = &HL[wgru][1][0];          // h_33 (33&1 = 1)
            short8b a0 = *reinterpret_cast<const short8b*>(&pb[aoff0]);
            short8b a1 = *reinterpret_cast<const short8b*>(&pb[aoff1]);
            f32x4 accT = __builtin_amdgcn_mfma_f32_16x16x32_bf16(
                a0, *reinterpret_cast<const short8b*>(WFl + 24*512), zero4, 0,0,0);
            accT = __builtin_amdgcn_mfma_f32_16x16x32_bf16(
                a1, *reinterpret_cast<const short8b*>(WFl + 25*512), accT, 0,0,0);
            f32x4 accM = __builtin_amdgcn_mfma_f32_16x16x32_bf16(
                a0, *reinterpret_cast<const short8b*>(WFl + 26*512), zero4, 0,0,0);
            accM = __builtin_amdgcn_mfma_f32_16x16x32_bf16(
                a1, *reinterpret_cast<const short8b*>(WFl + 27*512), accM, 0,0,0);
            #pragma unroll
            for (int q = 0; q < 4; ++q) {
                int rloc = lhi*4 + q;
                uint2 hq = *reinterpret_cast<const uint2*>(
                    &pb[rloc*64 + ((l16*4) ^ (hswz(rloc) << 3))]);
                float g0 = __uint_as_float(hq.x << 16);
                float g1 = __uint_as_float(hq.x & 0xFFFF0000u);
                float g2 = __uint_as_float(hq.y << 16);
                float g3 = __uint_as_float(hq.y & 0xFFFF0000u);
                float eT = fexp2(accT[q]);
                float eM = fexp2(accM[q]);
                denT[q] += eT; denM[q] += eM;
                numT2[q][0].x = fmaf(eT, g0, numT2[q][0].x);
                numT2[q][0].y = fmaf(eT, g1, numT2[q][0].y);
                numT2[q][1].x = fmaf(eT, g2, numT2[q][1].x);
                numT2[q][1].y = fmaf(eT, g3, numT2[q][1].y);
                numM2[q][0].x = fmaf(eM, g0, numM2[q][0].x);
                numM2[q][0].y = fmaf(eM, g1, numM2[q][0].y);
                numM2[q][1].x = fmaf(eM, g2, numM2[q][1].x);
                numM2[q][1].y = fmaf(eM, g3, numM2[q][1].y);
            }
        }
        const int rowbase = blockIdx.x*64 + wgru*16;
        #pragma unroll
        for (int q = 0; q < 4; ++q) {
            int row = rowbase + lhi*4 + q;
            float rT = frcp(denT[q]), rM = frcp(denM[q]);
            #pragma unroll
            for (int j = 0; j < 2; ++j) {
                hT_out[row*HD + (2*j  )*16 + l16] = numT2[q][j].x*rT;
                hT_out[row*HD + (2*j+1)*16 + l16] = numT2[q][j].y*rT;
                hM_out[row*HD + (2*j  )*16 + l16] = numM2[q][j].x*rM;
                hM_out[row*HD + (2*j+1)*16 + l16] = numM2[q][j].y*rM;
            }
        }
    }
}

// ---------------- Kernel B: MFMA MLP heads + T10/M0 + X_out (unchanged) ----------------
__global__ __launch_bounds__(256)
void mlp_mfma(const float* __restrict__ hT, const float* __restrict__ hM,
    const float* __restrict__ TW1, const float* __restrict__ Tb1,
    const float* __restrict__ TW2, const float* __restrict__ Tb2,
    const float* __restrict__ TW3, const float* __restrict__ Tb3,
    const float* __restrict__ MW1, const float* __restrict__ Mb1,
    const float* __restrict__ MW2, const float* __restrict__ Mb2,
    const float* __restrict__ MW3, const float* __restrict__ Mb3,
    const float* __restrict__ FA, const float* __restrict__ TR,
    float* __restrict__ out)
{
    __shared__ __align__(16) unsigned short xh[2*64*64];
    __shared__ __align__(16) unsigned short h1s[64*256];
    __shared__ float praw[4][64];
    __shared__ float rawv[2][64];
    __shared__ float Es[64], M0s[64];

    const int tid  = threadIdx.x;
    const int lane = tid & 63;
    const int wv   = tid >> 6;
    const int l16  = lane & 15;
    const int lhi  = lane >> 4;
    const int row0 = blockIdx.x*64;

    {
        int r  = tid >> 2;
        int k0 = (tid & 3) * 16;
        int rx = r & 7;
        const float* pT = &hT[(row0+r)*64 + k0];
        const float* pM = &hM[(row0+r)*64 + k0];
        #pragma unroll
        for (int j = 0; j < 4; ++j) {
            float4 vT = *reinterpret_cast<const float4*>(pT + 4*j);
            float4 vM = *reinterpret_cast<const float4*>(pM + 4*j);
            int kk = k0 + 4*j;
            int ad = r*64 + ((((kk>>3) ^ rx))<<3) + (kk&7);
            short4b sT = { (short)f2bf_rne(vT.x), (short)f2bf_rne(vT.y),
                           (short)f2bf_rne(vT.z), (short)f2bf_rne(vT.w) };
            short4b sM = { (short)f2bf_rne(vM.x), (short)f2bf_rne(vM.y),
                           (short)f2bf_rne(vM.z), (short)f2bf_rne(vM.w) };
            *reinterpret_cast<short4b*>(&xh[ad])        = sT;
            *reinterpret_cast<short4b*>(&xh[4096 + ad]) = sM;
        }
        for (int i = tid; i < 64*24; i += 256) {
            int rr = i / 24, kk = 200 + i % 24;
            h1s[rr*256 + ((((kk>>3) ^ (rr&7)))<<3) + (kk&7)] = 0;
        }
    }
    __syncthreads();

    for (int brn = 0; brn < 2; ++brn) {
        const float* W1 = brn ? MW1 : TW1; const float* b1 = brn ? Mb1 : Tb1;
        const float* W2 = brn ? MW2 : TW2; const float* b2 = brn ? Mb2 : Tb2;
        const float* W3 = brn ? MW3 : TW3; const float* b3 = brn ? Mb3 : Tb3;

        for (int s = 0; s < 4; ++s) {
            int nt = wv + 4*s;
            if (nt > 12) break;
            int n  = nt*16 + l16;
            int nc = n < 200 ? n : 199;
            float bv = b1[nc];
            f32x4 acc[4];
            #pragma unroll
            for (int mt = 0; mt < 4; ++mt) acc[mt] = (f32x4){bv,bv,bv,bv};
            #pragma unroll
            for (int ks = 0; ks < 2; ++ks) {
                int k0 = ks*32 + lhi*8;
                const float* wp = &W1[nc*64 + k0];
                float4 w0 = *reinterpret_cast<const float4*>(wp);
                float4 w1 = *reinterpret_cast<const float4*>(wp + 4);
                short8b bh, bl;
                split8(w0, w1, bh, bl);
                #pragma unroll
                for (int mt = 0; mt < 4; ++mt) {
                    int rr = mt*16 + l16;
                    short8b a = *reinterpret_cast<const short8b*>(
                        &xh[brn*4096 + rr*64 + ((((k0>>3) ^ (rr&7)))<<3)]);
                    acc[mt] = __builtin_amdgcn_mfma_f32_16x16x32_bf16(a, bh, acc[mt], 0,0,0);
                    acc[mt] = __builtin_amdgcn_mfma_f32_16x16x32_bf16(a, bl, acc[mt], 0,0,0);
                }
            }
            if (n < 200) {
                #pragma unroll
                for (int mt = 0; mt < 4; ++mt) {
                    #pragma unroll
                    for (int q = 0; q < 4; ++q) {
                        int rr = mt*16 + lhi*4 + q;
                        h1s[rr*256 + ((((n>>3) ^ (rr&7)))<<3) + (n&7)] =
                            f2bf_rne(felu(acc[mt][q]));
                    }
                }
            }
        }
        __syncthreads();

        float p[4][4] = {};
        for (int s = 0; s < 4; ++s) {
            int nt = wv + 4*s;
            if (nt > 12) break;
            int n  = nt*16 + l16;
            int nc = n < 200 ? n : 199;
            float w3v = (n < 200) ? W3[nc] : 0.0f;
            float bv = b2[nc];
            f32x4 acc[4];
            #pragma unroll
            for (int mt = 0; mt < 4; ++mt) acc[mt] = (f32x4){bv,bv,bv,bv};
            for (int ks = 0; ks < 7; ++ks) {
                int k0 = ks*32 + lhi*8;
                short8b bh, bl;
                if (k0 + 8 <= 200) {
                    const float* wp = &W2[nc*200 + k0];
                    float4 w0 = *reinterpret_cast<const float4*>(wp);
                    float4 w1 = *reinterpret_cast<const float4*>(wp + 4);
                    split8(w0, w1, bh, bl);
                } else {
                    #pragma unroll
                    for (int i = 0; i < 8; ++i) { bh[i] = 0; bl[i] = 0; }
                }
                #pragma unroll
                for (int mt = 0; mt < 4; ++mt) {
                    int rr = mt*16 + l16;
                    short8b a = *reinterpret_cast<const short8b*>(
                        &h1s[rr*256 + ((((k0>>3) ^ (rr&7)))<<3)]);
                    acc[mt] = __builtin_amdgcn_mfma_f32_16x16x32_bf16(a, bh, acc[mt], 0,0,0);
                    acc[mt] = __builtin_amdgcn_mfma_f32_16x16x32_bf16(a, bl, acc[mt], 0,0,0);
                }
            }
            #pragma unroll
            for (int mt = 0; mt < 4; ++mt)
                #pragma unroll
                for (int q = 0; q < 4; ++q)
                    p[mt][q] = fmaf(w3v, felu(acc[mt][q]), p[mt][q]);
        }
        #pragma unroll
        for (int off = 1; off < 16; off <<= 1) {
            #pragma unroll
            for (int mt = 0; mt < 4; ++mt)
                #pragma unroll
                for (int q = 0; q < 4; ++q)
                    p[mt][q] += __shfl_xor(p[mt][q], off);
        }
        if (l16 == 0) {
            #pragma unroll
            for (int mt = 0; mt < 4; ++mt)
                #pragma unroll
                for (int q = 0; q < 4; ++q)
                    praw[wv][mt*16 + lhi*4 + q] = p[mt][q];
        }
        __syncthreads();
        if (tid < 64)
            rawv[brn][tid] = b3[0] + praw[0][tid] + praw[1][tid] + praw[2][tid] + praw[3][tid];
        __syncthreads();
    }

    if (tid < 64) {
        int row = row0 + tid;
        float T10 = 0.1f + 4.9f*fsigmoid(rawv[0][tid]);
        float M0  = 10000.0f*fsigmoid(rawv[1][tid]);
        Es[tid]  = __expf(-TR[row]/T10);
        M0s[tid] = M0;
        out[(size_t)B_TOT*T_LEN + row]         = T10;
        out[(size_t)B_TOT*T_LEN + B_TOT + row] = M0;
    }
    __syncthreads();
    for (int i = tid; i < 64*T_LEN; i += 256) {
        int rr = i / T_LEN, t = i - rr*T_LEN;
        int row = row0 + rr;
        float fa = FA[row*T_LEN + t];
        float s = __sinf(fa), c = __cosf(fa);
        float Ev = Es[rr];
        out[row*T_LEN + t] = (1.0f - Ev)*s*frcp(1.0f - c*Ev)*M0s[rr];
    }
}

extern "C" void kernel_launch(void* const* d_in, const int* in_sizes, int n_in,
                              void* d_out, int out_size, void* d_ws, size_t ws_size,
                              hipStream_t stream) {
    const float* Xin = (const float*)d_in[0];
    const float* FA  = (const float*)d_in[1];
    const float* TR  = (const float*)d_in[4];
    const float* Wih = (const float*)d_in[5];
    const float* Whh = (const float*)d_in[6];
    const float* bih = (const float*)d_in[7];
    const float* bhh = (const float*)d_in[8];
    const float* swT = (const float*)d_in[9];
    const float* swM = (const float*)d_in[10];
    const float* TW1 = (const float*)d_in[11]; const float* Tb1 = (const float*)d_in[12];
    const float* TW2 = (const float*)d_in[13]; const float* Tb2 = (const float*)d_in[14];
    const float* TW3 = (const float*)d_in[15]; const float* Tb3 = (const float*)d_in[16];
    const float* MW1 = (const float*)d_in[17]; const float* Mb1 = (const float*)d_in[18];
    const float* MW2 = (const float*)d_in[19]; const float* Mb2 = (const float*)d_in[20];
    const float* MW3 = (const float*)d_in[21]; const float* Mb3 = (const float*)d_in[22];
    float* out = (float*)d_out;

    float* hT = (float*)d_ws;
    float* hM = hT + (size_t)B_TOT*HD;

    gru_attn_mfma<<<B_TOT/64, 512, 0, stream>>>(Xin, FA, Wih, Whh, bih, bhh,
                                                swT, swM, hT, hM);
    mlp_mfma<<<B_TOT/64, 256, 0, stream>>>(hT, hM,
                                           TW1, Tb1, TW2, Tb2, TW3, Tb3,
                                           MW1, Mb1, MW2, Mb2, MW3, Mb3,
                                           FA, TR, out);
}